// Round 8
// baseline (102.579 us; speedup 1.0000x reference)
//
#include <hip/hip_runtime.h>
#include <math.h>

// QASA layer: out = circuit(x @ W_in.T + b_in, q_weights) @ W_out.T + b_out
// 8 qubits -> 256 complex amps.
//
// Round 8: SPILL ELIMINATION. Rounds 5-7 hoisted 32 float4 loads (128 VGPR)
// under a 128-VGPR launch-bounds cap -> forced scratch spills (HBM-backed)
// that silently cancelled every structural gain (3 neutral rounds). Phase 1
// reverts to streaming accumulation: W_in slices register-resident (32 VGPR),
// x loads feed FMAs directly; compiler pipelines within budget. Peak live
// ~100 VGPR < 128 -> no spills at 4 blocks/CU.
//
// Everything else = round 7: 32-lane-row layout (row A = lanes 0-31, row B =
// lanes 32-63; idx bits [7:3] = half-lane, [2:0] = 8 regs), CNOT ladders
// eliminated via F=I+S conjugation, layer 0 + embedding absorbed into
// product factors, phase-4 operand prefetch, cooperative GEMV phases.

typedef float f32x2 __attribute__((ext_vector_type(2)));

__device__ __forceinline__ int f2i(float v) { return __float_as_int(v); }
__device__ __forceinline__ float i2f(int v) { return __int_as_float(v); }

template <int CTRL>
__device__ __forceinline__ float dppf(float v) {
    return i2f(__builtin_amdgcn_update_dpp(0, f2i(v), CTRL, 0xF, 0xF, true));
}

// xor-mask cross-lane: DPP (VALU pipe) for 1,2,3,7,8,15; ds_swizzle <32; shfl 32
template <int ML>
__device__ __forceinline__ float gshm(float v) {
    static_assert(ML > 0 && ML < 64, "lane mask");
    if constexpr (ML == 1)       return dppf<0xB1>(v);    // quad_perm [1,0,3,2]
    else if constexpr (ML == 2)  return dppf<0x4E>(v);    // quad_perm [2,3,0,1]
    else if constexpr (ML == 3)  return dppf<0x1B>(v);    // quad_perm [3,2,1,0]
    else if constexpr (ML == 7)  return dppf<0x141>(v);   // row_half_mirror = xor7
    else if constexpr (ML == 8)  return dppf<0x128>(v);   // row_ror:8 = xor8
    else if constexpr (ML == 15) return dppf<0x140>(v);   // row_mirror = xor15
    else if constexpr (ML < 32)  return i2f(__builtin_amdgcn_ds_swizzle(f2i(v), 0x1F | (ML << 10)));
    else                         return __shfl_xor(v, 32, 64);
}

template <int L>
__device__ __forceinline__ float rdlane(float v) {
    return i2f(__builtin_amdgcn_readlane(f2i(v), L));
}

__device__ __forceinline__ float bpermf(int addr, float v) {
    return i2f(__builtin_amdgcn_ds_bpermute(addr, f2i(v)));
}

// Generalized gate on 8-reg state: RX about axis (lane-mask ML, reg-mask MR),
// then RZ with sign = parity(lane&ZL) ^ parity(reg&ZR). reg r = 2j + comp.
template <int ML, int MR, int ZL, int ZR>
__device__ __forceinline__ void ggate8(f32x2 re[4], f32x2 im[4],
                                       float c1, float s1, float c2, float s2,
                                       int lane) {
    constexpr int JM = MR >> 1;
    constexpr bool CM = (MR & 1) != 0;
    f32x2 pRe[4], pIm[4];
#pragma unroll
    for (int j = 0; j < 4; ++j) {
        f32x2 sR = re[j ^ JM], sI = im[j ^ JM];
        if constexpr (CM) { sR = sR.yx; sI = sI.yx; }
        if constexpr (ML != 0) {
            pRe[j].x = gshm<ML>(sR.x); pRe[j].y = gshm<ML>(sR.y);
            pIm[j].x = gshm<ML>(sI.x); pIm[j].y = gshm<ML>(sI.y);
        } else { pRe[j] = sR; pIm[j] = sI; }
    }
    float base;
    if constexpr (ZL == 0) base = -s2;
    else                   base = (__popc(lane & ZL) & 1) ? s2 : -s2;
#pragma unroll
    for (int j = 0; j < 4; ++j) {
        f32x2 nR = c1 * re[j] + s1 * pIm[j];
        f32x2 nI = c1 * im[j] - s1 * pRe[j];
        const int pj = __builtin_popcount(j & (ZR >> 1)) & 1;  // folds post-unroll
        float sj = pj ? -base : base;
        float sc = (ZR & 1) ? -sj : sj;
        f32x2 ss = { sj, sc };
        re[j] = c2 * nR - ss * nI;
        im[j] = c2 * nI + ss * nR;
    }
}

__global__ void __launch_bounds__(256, 4) qasa_kernel(
    const float* __restrict__ x, const float* __restrict__ W_in,
    const float* __restrict__ b_in, const float* __restrict__ qw,
    const float* __restrict__ W_out, const float* __restrict__ b_out,
    float* __restrict__ out)
{
    const int tid = threadIdx.x;
    const int lane = tid & 63;
    const int w = tid >> 6;                       // wave id in block
    const int block8 = blockIdx.x * 8;

    __shared__ float ang[64];                     // [q][8 rows]
    __shared__ float evs[8][8] __attribute__((aligned(16)));  // [row][ev]

    // per-wave layer trig, lane-indexed in VGPRs (qw has exactly 64 entries)
    float vc, vs;
    __sincosf(0.5f * qw[lane], &vs, &vc);

    const int b0 = lane & 1, b1 = (lane >> 1) & 1, b3 = (lane >> 3) & 1;
    const int qofl = b0 | (b1 << 1) | (b3 << 2);  // qubit index pattern (bits 0,1,3)
    const float binq = b_in[qofl];

    // ---- phase 1 (cooperative, STREAMING): wave w computes angles for
    //      q = 2w, 2w+1 over all 8 rows. W_in register-resident; x streams.
    {
        const float4* w4 = (const float4*)W_in;
        float4 wv0[4], wv1[4];
#pragma unroll
        for (int k = 0; k < 4; ++k) {
            wv0[k] = w4[(2 * w) * 256 + lane + 64 * k];
            wv1[k] = w4[(2 * w + 1) * 256 + lane + 64 * k];
        }
#pragma unroll
        for (int g = 0; g < 2; ++g) {
            const float4* xr = (const float4*)(x + (size_t)(block8 + 4 * g) * 1024);
            f32x2 acc2[8];
#pragma unroll
            for (int j = 0; j < 8; ++j) acc2[j] = (f32x2){0.f, 0.f};
#pragma unroll
            for (int r = 0; r < 4; ++r)
#pragma unroll
                for (int k = 0; k < 4; ++k) {
                    float4 xvv = xr[r * 256 + lane + 64 * k];
                    acc2[r]     += (f32x2){xvv.x, xvv.y} * (f32x2){wv0[k].x, wv0[k].y}
                                 + (f32x2){xvv.z, xvv.w} * (f32x2){wv0[k].z, wv0[k].w};
                    acc2[4 + r] += (f32x2){xvv.x, xvv.y} * (f32x2){wv1[k].x, wv1[k].y}
                                 + (f32x2){xvv.z, xvv.w} * (f32x2){wv1[k].z, wv1[k].w};
                }
            float acc[8];
#pragma unroll
            for (int j = 0; j < 8; ++j) {
                acc[j] = acc2[j].x + acc2[j].y;
                acc[j] += dppf<0xB1>(acc[j]);
                acc[j] += dppf<0x4E>(acc[j]);
                acc[j] += dppf<0x128>(acc[j]);
            }
            float t01 = b0 ? acc[1] : acc[0];
            float t23 = b0 ? acc[3] : acc[2];
            float t45 = b0 ? acc[5] : acc[4];
            float t67 = b0 ? acc[7] : acc[6];
            float ta = b1 ? t23 : t01;
            float tb = b1 ? t67 : t45;
            float S = b3 ? tb : ta;
            S += gshm<4>(S); S += gshm<16>(S); S += gshm<32>(S);
            if ((lane & 52) == 0)
                ang[(2 * w + ((lane >> 3) & 1)) * 8 + 4 * g + (lane & 3)] = S;
        }
    }
    __syncthreads();

    // ---- phase-4 operand prefetch (latency hides under the circuit) ----
    const int c4 = (w << 6) + lane;
    const float4* wo = (const float4*)W_out;
    float4 wa[4], wb[4];
#pragma unroll
    for (int c = 0; c < 4; ++c) {
        wa[c] = wo[2 * (4 * c4 + c)];
        wb[c] = wo[2 * (4 * c4 + c) + 1];
    }
    float4 bias = ((const float4*)b_out)[c4];

    // ---- phase 2a: per-wire factor = RZ(qz) RX(qx) RZ(a) RX(a) |0> ----
    // Row of this lane = w + 4*half (half = lane bit 5). Publishing lanes
    // per half: l5 in {0..3,8..11} hold u-factor of qubit qofl; l5 in
    // {16..19,24..27} hold v-factor of the same qubit.
    const int half32 = lane & 32;
    const int rowsel = w + ((lane >> 3) & 4);
    const int isV = (lane >> 4) & 1;
    float A = ang[qofl * 8 + rowsel] + binq;
    float ca, sa;
    __sincosf(0.5f * A, &sa, &ca);
    float ur = ca * ca, ui = -ca * sa, vr = sa * sa, vi = ui;
    const int a1 = 4 * qofl, a2 = 4 * (qofl + 8);
    float cx = bpermf(a1, vc);
    float sx = bpermf(a1, vs);
    float cz = bpermf(a2, vc);
    float sz = bpermf(a2, vs);
    // RX(qx): u' = cx*u - i sx*v ; v' = cx*v - i sx*u
    float ur1 = cx * ur + sx * vi, ui1 = cx * ui - sx * vr;
    float vr1 = cx * vr + sx * ui, vi1 = cx * vi - sx * ur;
    // RZ(qz): u'' = (cz - i sz) u' ; v'' = (cz + i sz) v'
    float ur2 = cz * ur1 + sz * ui1, ui2 = cz * ui1 - sz * ur1;
    float vr2 = cz * vr1 - sz * vi1, vi2 = cz * vi1 + sz * vr1;
    const float fre = isV ? vr2 : ur2;
    const float fim = isV ? vi2 : ui2;

    // ---- phase 2b-init: product expansion (state after layer 0) ----
    // wires 0-4 -> half-lane bits 4..0 (factor lanes 0,1,2,3,8);
    // wires 5,6,7 -> reg bits 2,1,0 (factor lanes 9,10,11).
    float Pr, Pi;
    {
        int b = (lane >> 4) & 1;                       // wire0: l5 bit4
        int a = (half32 | (b << 4)) << 2;              // L=0
        Pr = bpermf(a, fre); Pi = bpermf(a, fim);
    }
#define PM(L_, SH_) { \
        int b = (lane >> (SH_)) & 1; \
        int a = (half32 + (L_) + (b << 4)) << 2; \
        float fr = bpermf(a, fre), fi = bpermf(a, fim); \
        float tr = Pr * fr - Pi * fi; \
        Pi = Pr * fi + Pi * fr; Pr = tr; }
    PM(1, 3) PM(2, 2) PM(3, 1) PM(8, 0)
#undef PM
    f32x2 re[4], im[4];
    {
        int a5u = (half32 + 9) << 2,  a5v = (half32 + 25) << 2;
        int a6u = (half32 + 10) << 2, a6v = (half32 + 26) << 2;
        int a7u = (half32 + 11) << 2, a7v = (half32 + 27) << 2;
        float u5r = bpermf(a5u, fre), u5i = bpermf(a5u, fim);
        float v5r = bpermf(a5v, fre), v5i = bpermf(a5v, fim);
        float u6r = bpermf(a6u, fre), u6i = bpermf(a6u, fim);
        float v6r = bpermf(a6v, fre), v6i = bpermf(a6v, fim);
        float u7r = bpermf(a7u, fre), u7i = bpermf(a7u, fim);
        float v7r = bpermf(a7v, fre), v7i = bpermf(a7v, fim);
        // h[b6<<1|b7] = f6 x f7
        float hr[4], hi[4];
        hr[0] = u6r * u7r - u6i * u7i;  hi[0] = u6r * u7i + u6i * u7r;
        hr[1] = u6r * v7r - u6i * v7i;  hi[1] = u6r * v7i + u6i * v7r;
        hr[2] = v6r * u7r - v6i * u7i;  hi[2] = v6r * u7i + v6i * u7r;
        hr[3] = v6r * v7r - v6i * v7i;  hi[3] = v6r * v7i + v6i * v7r;
        float rr[8], ii[8];
#pragma unroll
        for (int r = 0; r < 8; ++r) {
            float f5r = (r & 4) ? v5r : u5r, f5i = (r & 4) ? v5i : u5i;
            float gr = f5r * hr[r & 3] - f5i * hi[r & 3];
            float gi = f5r * hi[r & 3] + f5i * hr[r & 3];
            rr[r] = Pr * gr - Pi * gi;
            ii[r] = Pr * gi + Pi * gr;
        }
#pragma unroll
        for (int j = 0; j < 4; ++j) {
            re[j] = (f32x2){ rr[2 * j], rr[2 * j + 1] };
            im[j] = (f32x2){ ii[2 * j], ii[2 * j + 1] };
        }
    }

    // ---- phase 2b: layers 2-4, one SIMT stream covers both rows ----
    // qw[l][0][i] -> lane 16l+i (RX), qw[l][1][i] -> lane 16l+8+i (RZ)
#define GG(Lx, W_, ML_, MR_, ZL_, ZR_) { \
    float c1 = rdlane<16 * (Lx) + (W_)>(vc), s1 = rdlane<16 * (Lx) + (W_)>(vs); \
    float c2 = rdlane<16 * (Lx) + 8 + (W_)>(vc), s2 = rdlane<16 * (Lx) + 8 + (W_)>(vs); \
    ggate8<ML_, MR_, ZL_, ZR_>(re, im, c1, s1, c2, s2, lane); }

    // layer 2 (a=1): axis {k,k-1}; RZ rows {k..7}
    GG(1,0, 24,0, 16,0)  GG(1,1, 12,0, 24,0)  GG(1,2, 6,0, 28,0)  GG(1,3, 3,0, 30,0)
    GG(1,4, 1,4, 31,0)   GG(1,5, 0,6, 31,4)   GG(1,6, 0,3, 31,6)  GG(1,7, 0,1, 31,7)
    // layer 3 (a=2): axis {k,k-2}; RZ rows {k,k+2,k+4,k+6}
    GG(2,0, 20,0, 16,0)  GG(2,1, 10,0, 8,0)   GG(2,2, 5,0, 20,0)  GG(2,3, 2,4, 10,0)
    GG(2,4, 1,2, 21,0)   GG(2,5, 0,5, 10,4)   GG(2,6, 0,2, 21,2)  GG(2,7, 0,1, 10,5)
    // layer 4 (a=3): axis {k..k-3}; RZ rows {k,k+1,k+4,k+5}
    GG(3,0, 30,0, 16,0)  GG(3,1, 15,0, 24,0)  GG(3,2, 7,4, 12,0)  GG(3,3, 3,6, 6,0)
    GG(3,4, 1,7, 19,0)   GG(3,5, 0,7, 25,4)   GG(3,6, 0,3, 12,6)  GG(3,7, 0,1, 6,3)
#undef GG

    // ---- phase 3: expvals (F^-4 masks row_k = {k,k+4}), per 32-lane half ----
    {
        f32x2 pp0 = re[0] * re[0] + im[0] * im[0];
        f32x2 pp1 = re[1] * re[1] + im[1] * im[1];
        f32x2 pp2 = re[2] * re[2] + im[2] * im[2];
        f32x2 pp3 = re[3] * re[3] + im[3] * im[3];
        float sx0 = pp0.x + pp0.y, dx0 = pp0.x - pp0.y;
        float sx1 = pp1.x + pp1.y, dx1 = pp1.x - pp1.y;
        float sx2 = pp2.x + pp2.y, dx2 = pp2.x - pp2.y;
        float sx3 = pp3.x + pp3.y, dx3 = pp3.x - pp3.y;
        float q0 = (sx0 + sx1) + (sx2 + sx3);          // reg-mask 0
        float q1 = (dx0 + dx1) + (dx2 + dx3);          // reg-mask 1 (r bit0)
        float q2 = (sx0 - sx1) + (sx2 - sx3);          // reg-mask 2 (r bit1)
        float q4 = (sx0 + sx1) - (sx2 + sx3);          // reg-mask 4 (r bit2)

        // q0: full signed Walsh over half-lane bits 0..4
        { float u = dppf<0xB1>(q0);  q0 = (lane & 1)  ? (u - q0) : (q0 + u); }
        { float u = dppf<0x4E>(q0);  q0 = (lane & 2)  ? (u - q0) : (q0 + u); }
        { float u = gshm<4>(q0);     q0 = (lane & 4)  ? (u - q0) : (q0 + u); }
        { float u = dppf<0x128>(q0); q0 = (lane & 8)  ? (u - q0) : (q0 + u); }
        { float u = gshm<16>(q0);    q0 = (lane & 16) ? (u - q0) : (q0 + u); }
        // q4: signed at bit3 only
        q4 += dppf<0xB1>(q4); q4 += dppf<0x4E>(q4); q4 += gshm<4>(q4);
        { float u = dppf<0x128>(q4); q4 = (lane & 8) ? (u - q4) : (q4 + u); }
        q4 += gshm<16>(q4);
        // q2: signed at bit2 only
        q2 += dppf<0xB1>(q2); q2 += dppf<0x4E>(q2);
        { float u = gshm<4>(q2); q2 = (lane & 4) ? (u - q2) : (q2 + u); }
        q2 += dppf<0x128>(q2); q2 += gshm<16>(q2);
        // q1: signed at bit1 only
        q1 += dppf<0xB1>(q1);
        { float u = dppf<0x4E>(q1); q1 = (lane & 2) ? (u - q1) : (q1 + u); }
        q1 += gshm<4>(q1); q1 += dppf<0x128>(q1); q1 += gshm<16>(q1);

        const int l5 = lane & 31;
        const int row = rowsel;
        if (l5 == 16)      { evs[row][0] = q0; }
        else if (l5 == 8)  { evs[row][1] = q0; evs[row][5] = q4; }
        else if (l5 == 4)  { evs[row][2] = q0; evs[row][6] = q2; }
        else if (l5 == 2)  { evs[row][3] = q0; evs[row][7] = q1; }
        else if (l5 == 17) { evs[row][4] = q0; }
    }
    __syncthreads();

    // ---- phase 4 (cooperative): wave w owns cols [256w,256w+256) for all
    //      8 rows; operands already in registers (prefetched).
    {
#pragma unroll
        for (int r = 0; r < 8; ++r) {
            const float4* ev4 = (const float4*)evs[r];
            float4 lo = ev4[0], hi = ev4[1];
            f32x2 E01 = { lo.x, lo.y }, E23 = { lo.z, lo.w };
            f32x2 E45 = { hi.x, hi.y }, E67 = { hi.z, hi.w };
            float res[4];
#pragma unroll
            for (int c = 0; c < 4; ++c) {
                f32x2 a2v = E01 * (f32x2){ wa[c].x, wa[c].y } + E23 * (f32x2){ wa[c].z, wa[c].w }
                          + E45 * (f32x2){ wb[c].x, wb[c].y } + E67 * (f32x2){ wb[c].z, wb[c].w };
                res[c] = a2v.x + a2v.y;
            }
            float4 o;
            o.x = bias.x + res[0]; o.y = bias.y + res[1];
            o.z = bias.z + res[2]; o.w = bias.w + res[3];
            ((float4*)(out + (size_t)(block8 + r) * 1024))[c4] = o;
        }
    }
}

extern "C" void kernel_launch(void* const* d_in, const int* in_sizes, int n_in,
                              void* d_out, int out_size, void* d_ws, size_t ws_size,
                              hipStream_t stream) {
    const float* x     = (const float*)d_in[0];
    const float* W_in  = (const float*)d_in[1];
    const float* b_in  = (const float*)d_in[2];
    const float* qw    = (const float*)d_in[3];
    const float* W_out = (const float*)d_in[4];
    const float* b_out = (const float*)d_in[5];
    float* outp = (float*)d_out;

    const int B = in_sizes[0] / 1024;   // 8192 rows
    const int grid = B / 8;             // 8 rows per 256-thread block
    qasa_kernel<<<grid, 256, 0, stream>>>(x, W_in, b_in, qw, W_out, b_out, outp);
}